// Round 2
// baseline (1266.394 us; speedup 1.0000x reference)
//
#include <hip/hip_runtime.h>

typedef unsigned short u16;
typedef __attribute__((ext_vector_type(8))) short short8;
typedef __attribute__((ext_vector_type(4))) float f32x4;

__device__ __forceinline__ u16 f2bf(float x) {
  unsigned u = __float_as_uint(x);
  u += 0x7FFFu + ((u >> 16) & 1u);   // RNE
  return (u16)(u >> 16);
}
__device__ __forceinline__ float bf2f(u16 x) {
  return __uint_as_float(((unsigned)x) << 16);
}

#define GLOAD_LDS16(g, l)                                                      \
  __builtin_amdgcn_global_load_lds(                                            \
      (const __attribute__((address_space(1))) void*)(g),                      \
      (__attribute__((address_space(3))) void*)(l), 16, 0, 0)

// ---------------- f32 -> bf16 convert ----------------
__global__ void cvt_f32_bf16(const float* __restrict__ in, u16* __restrict__ out, int n4) {
  int i = blockIdx.x * blockDim.x + threadIdx.x;
  int stride = gridDim.x * blockDim.x;
  for (; i < n4; i += stride) {
    float4 f = ((const float4*)in)[i];
    ushort4 o;
    o.x = f2bf(f.x); o.y = f2bf(f.y); o.z = f2bf(f.z); o.w = f2bf(f.w);
    ((ushort4*)out)[i] = o;
  }
}

// ---------------- l [B,768,256] f32 -> lT [B,256,768] bf16 ----------------
__global__ void transpose_l(const float* __restrict__ in, u16* __restrict__ out) {
  __shared__ float tile[32][33];
  int t0 = blockIdx.x * 32, c0 = blockIdx.y * 32, b = blockIdx.z;
  int tx = threadIdx.x, ty = threadIdx.y;
  #pragma unroll
  for (int j = 0; j < 32; j += 8)
    tile[ty + j][tx] = in[((size_t)b * 768 + c0 + ty + j) * 256 + t0 + tx];
  __syncthreads();
  #pragma unroll
  for (int j = 0; j < 32; j += 8)
    out[((size_t)b * 256 + t0 + ty + j) * 768 + c0 + tx] = f2bf(tile[tx][ty + j]);
}

// ---------------- vT [B,256,1024] bf16 -> v [B,1024,256] bf16 ----------------
__global__ void transpose_v(const u16* __restrict__ in, u16* __restrict__ out) {
  __shared__ u16 tile[32][33];
  int t0 = blockIdx.x * 32, v0 = blockIdx.y * 32, b = blockIdx.z;
  int tx = threadIdx.x, ty = threadIdx.y;
  #pragma unroll
  for (int j = 0; j < 32; j += 8)
    tile[ty + j][tx] = in[((size_t)b * 256 + t0 + ty + j) * 1024 + v0 + tx];
  __syncthreads();
  #pragma unroll
  for (int j = 0; j < 32; j += 8)
    out[((size_t)b * 1024 + v0 + ty + j) * 256 + t0 + tx] = tile[tx][ty + j];
}

// ---------------- bf16 GEMM: C[M,N] = A[M,K] * B[N,K]^T + bias, C bf16 ----------------
// 128x128 tile, BK=64, 4 waves (2x2), each wave 64x64 = 4x4 mfma frags.
// global_load_lds w16 staging, XOR-swizzled source (linear LDS dest), swizzled ds_read.
__global__ __launch_bounds__(256, 2) void gemm_bt(
    const u16* __restrict__ A, const u16* __restrict__ Bw,
    const float* __restrict__ bias, u16* __restrict__ C,
    int M, int N, int Kd) {
  __shared__ u16 lds[2 * 128 * 64];  // A tile then B tile, 32 KB
  const int tid = threadIdx.x;
  const int lane = tid & 63, wv = tid >> 6;
  const int wr = wv >> 1, wc = wv & 1;
  const int m0 = blockIdx.y * 128, n0 = blockIdx.x * 128;
  const int l8 = lane >> 3, l7 = lane & 7;
  const int srcCol = 8 * (l7 ^ l8);    // pre-swizzled source column (elems)
  const int lq = lane >> 4, lr = lane & 15;

  f32x4 acc[4][4];
  #pragma unroll
  for (int m = 0; m < 4; ++m)
    #pragma unroll
    for (int n = 0; n < 4; ++n) acc[m][n] = (f32x4){0.f, 0.f, 0.f, 0.f};

  for (int k0 = 0; k0 < Kd; k0 += 64) {
    #pragma unroll
    for (int c = 0; c < 4; ++c) {
      int chunk = wv * 4 + c;            // 0..15 across waves
      int row = chunk * 8 + l8;          // tile row 0..127
      const u16* ga = A + (size_t)(m0 + row) * Kd + k0 + srcCol;
      GLOAD_LDS16(ga, &lds[chunk * 512]);
      const u16* gb = Bw + (size_t)(n0 + row) * Kd + k0 + srcCol;
      GLOAD_LDS16(gb, &lds[8192 + chunk * 512]);
    }
    __syncthreads();
    #pragma unroll
    for (int kk = 0; kk < 2; ++kk) {
      short8 af[4], bf[4];
      #pragma unroll
      for (int m = 0; m < 4; ++m) {
        int row = wr * 64 + m * 16 + lr;
        int cb = (kk * 64 + lq * 16) ^ ((row & 7) << 4);
        af[m] = *(const short8*)((const char*)lds + row * 128 + cb);
      }
      #pragma unroll
      for (int n = 0; n < 4; ++n) {
        int row = wc * 64 + n * 16 + lr;
        int cb = (kk * 64 + lq * 16) ^ ((row & 7) << 4);
        bf[n] = *(const short8*)((const char*)lds + 16384 + row * 128 + cb);
      }
      #pragma unroll
      for (int m = 0; m < 4; ++m)
        #pragma unroll
        for (int n = 0; n < 4; ++n)
          acc[m][n] = __builtin_amdgcn_mfma_f32_16x16x32_bf16(af[m], bf[n], acc[m][n], 0, 0, 0);
    }
    __syncthreads();
  }
  #pragma unroll
  for (int n = 0; n < 4; ++n) {
    int col = n0 + wc * 64 + n * 16 + lr;
    float bvv = bias[col];
    #pragma unroll
    for (int m = 0; m < 4; ++m) {
      int rbase = m0 + wr * 64 + m * 16 + 4 * lq;
      #pragma unroll
      for (int ii = 0; ii < 4; ++ii)
        C[(size_t)(rbase + ii) * N + col] = f2bf(acc[m][n][ii] + bvv);
    }
  }
}

// ---------------- GroupNorm stats: partial sums over 256-row chunks ----------------
// y [16][4096][1024] bf16; grid (chunk=16, b=16), block 256, thread owns 4 channels.
__global__ void gn_stats_partial(const u16* __restrict__ y, float* __restrict__ psum,
                                 float* __restrict__ psq) {
  int b = blockIdx.y, ch = blockIdx.x, t = threadIdx.x;
  int c = t * 4;
  float s0 = 0, s1 = 0, s2 = 0, s3 = 0, q0 = 0, q1 = 0, q2 = 0, q3 = 0;
  const u16* base = y + ((size_t)b * 4096 + (size_t)ch * 256) * 1024 + c;
  for (int n = 0; n < 256; ++n) {
    ushort4 u = *(const ushort4*)(base + (size_t)n * 1024);
    float f0 = bf2f(u.x), f1 = bf2f(u.y), f2 = bf2f(u.z), f3 = bf2f(u.w);
    s0 += f0; q0 += f0 * f0;
    s1 += f1; q1 += f1 * f1;
    s2 += f2; q2 += f2 * f2;
    s3 += f3; q3 += f3 * f3;
  }
  size_t o = ((size_t)(b * 16 + ch)) * 1024 + c;
  psum[o + 0] = s0; psum[o + 1] = s1; psum[o + 2] = s2; psum[o + 3] = s3;
  psq[o + 0] = q0;  psq[o + 1] = q1;  psq[o + 2] = q2;  psq[o + 3] = q3;
}

__global__ void gn_stats_final(const float* __restrict__ psum, const float* __restrict__ psq,
                               float* __restrict__ mean, float* __restrict__ rstd) {
  int i = blockIdx.x * blockDim.x + threadIdx.x;  // b*1024 + c, 16384 total
  if (i >= 16384) return;
  int b = i >> 10, c = i & 1023;
  float s = 0, q = 0;
  #pragma unroll
  for (int ch = 0; ch < 16; ++ch) {
    s += psum[(size_t)(b * 16 + ch) * 1024 + c];
    q += psq[(size_t)(b * 16 + ch) * 1024 + c];
  }
  float m = s * (1.f / 4096.f);
  float var = q * (1.f / 4096.f) - m * m;
  mean[i] = m;
  rstd[i] = rsqrtf(var + 1e-5f);
}

// ---------------- normalize in place (bf16) ----------------
__global__ void gn_norm_bf16(u16* __restrict__ y, const float* __restrict__ mean,
                             const float* __restrict__ rstd, const float* __restrict__ gamma,
                             const float* __restrict__ beta) {
  int idx = blockIdx.x * blockDim.x + threadIdx.x;
  int stride = gridDim.x * blockDim.x;
  for (; idx < 16777216; idx += stride) {
    size_t i4 = (size_t)idx * 4;
    int b = (int)(i4 >> 22);
    int c = (int)(i4 & 1023);
    ushort4 u = ((ushort4*)y)[idx];
    const float* mb = mean + b * 1024 + c;
    const float* rb = rstd + b * 1024 + c;
    ushort4 o;
    o.x = f2bf((bf2f(u.x) - mb[0]) * rb[0] * gamma[c + 0] + beta[c + 0]);
    o.y = f2bf((bf2f(u.y) - mb[1]) * rb[1] * gamma[c + 1] + beta[c + 1]);
    o.z = f2bf((bf2f(u.z) - mb[2]) * rb[2] * gamma[c + 2] + beta[c + 2]);
    o.w = f2bf((bf2f(u.w) - mb[3]) * rb[3] * gamma[c + 3] + beta[c + 3]);
    ((ushort4*)y)[idx] = o;
  }
}

// ---------------- normalize to f32 output ----------------
__global__ void gn_norm_f32(const u16* __restrict__ y, const float* __restrict__ mean,
                            const float* __restrict__ rstd, const float* __restrict__ gamma,
                            const float* __restrict__ beta, float* __restrict__ out) {
  int idx = blockIdx.x * blockDim.x + threadIdx.x;
  int stride = gridDim.x * blockDim.x;
  for (; idx < 16777216; idx += stride) {
    size_t i4 = (size_t)idx * 4;
    int b = (int)(i4 >> 22);
    int c = (int)(i4 & 1023);
    ushort4 u = ((const ushort4*)y)[idx];
    const float* mb = mean + b * 1024 + c;
    const float* rb = rstd + b * 1024 + c;
    float4 f;
    f.x = (bf2f(u.x) - mb[0]) * rb[0] * gamma[c + 0] + beta[c + 0];
    f.y = (bf2f(u.y) - mb[1]) * rb[1] * gamma[c + 1] + beta[c + 1];
    f.z = (bf2f(u.z) - mb[2]) * rb[2] * gamma[c + 2] + beta[c + 2];
    f.w = (bf2f(u.w) - mb[3]) * rb[3] * gamma[c + 3] + beta[c + 3];
    ((float4*)out)[idx] = f;
  }
}

// ---------------- fused attention ----------------
// grid (HW/64, H, B), block 256 (4 waves); wave owns 16 q-rows.
// S = q·kT^T (full 256 cols, K staged in 2 LDS halves), fp32 softmax,
// P->LDS (swizzled), PV vs V[dv][t] staged in 2 halves.
__global__ __launch_bounds__(256, 2) void attn_kernel(
    const u16* __restrict__ qn, const u16* __restrict__ kT,
    const u16* __restrict__ v, u16* __restrict__ o) {
  __shared__ alignas(16) char smem[65536];  // [0,32K): K/V tile; [32K,64K): P per wave
  const int tid = threadIdx.x;
  const int lane = tid & 63, wv = tid >> 6;
  const int lq = lane >> 4, lr = lane & 15;
  const int bx = blockIdx.x, h = blockIdx.y, b = blockIdx.z;
  const int nbase = bx * 64 + wv * 16;

  short8 aq[4];
  {
    const u16* qrow = qn + ((size_t)(b * 4096 + nbase + lr)) * 1024 + h * 128;
    #pragma unroll
    for (int kk = 0; kk < 4; ++kk) aq[kk] = *(const short8*)(qrow + kk * 32 + lq * 8);
  }

  f32x4 accs[16];
  #pragma unroll
  for (int i = 0; i < 16; ++i) accs[i] = (f32x4){0.f, 0.f, 0.f, 0.f};

  #pragma unroll
  for (int th = 0; th < 2; ++th) {
    __syncthreads();
    #pragma unroll
    for (int it = 0; it < 8; ++it) {
      int chunk = it * 256 + tid;        // 2048 chunks: 128 rows x 16 slots
      int row = chunk >> 4, slot = chunk & 15;
      short8 val = *(const short8*)(kT + ((size_t)(b * 256 + th * 128 + row)) * 1024 + h * 128 + slot * 8);
      *(short8*)(smem + row * 256 + ((slot * 16) ^ ((row & 7) << 4))) = val;
    }
    __syncthreads();
    #pragma unroll
    for (int tb = 0; tb < 8; ++tb) {
      #pragma unroll
      for (int kk = 0; kk < 4; ++kk) {
        int trow = tb * 16 + lr;
        short8 bk = *(const short8*)(smem + trow * 256 + ((kk * 64 + lq * 16) ^ ((trow & 7) << 4)));
        accs[th * 8 + tb] = __builtin_amdgcn_mfma_f32_16x16x32_bf16(aq[kk], bk, accs[th * 8 + tb], 0, 0, 0);
      }
    }
  }

  // softmax over 256 cols (scale 1024^-0.5 folded into exp2)
  const float c1 = 0.03125f * 1.44269504f;
  float mx[4], sm[4], rs[4];
  #pragma unroll
  for (int ii = 0; ii < 4; ++ii) {
    float m = accs[0][ii];
    #pragma unroll
    for (int tb = 1; tb < 16; ++tb) m = fmaxf(m, accs[tb][ii]);
    m = fmaxf(m, __shfl_xor(m, 1, 64));
    m = fmaxf(m, __shfl_xor(m, 2, 64));
    m = fmaxf(m, __shfl_xor(m, 4, 64));
    m = fmaxf(m, __shfl_xor(m, 8, 64));
    mx[ii] = m; sm[ii] = 0.f;
  }
  #pragma unroll
  for (int tb = 0; tb < 16; ++tb)
    #pragma unroll
    for (int ii = 0; ii < 4; ++ii) {
      float p = exp2f((accs[tb][ii] - mx[ii]) * c1);
      accs[tb][ii] = p;
      sm[ii] += p;
    }
  #pragma unroll
  for (int ii = 0; ii < 4; ++ii) {
    float s = sm[ii];
    s += __shfl_xor(s, 1, 64);
    s += __shfl_xor(s, 2, 64);
    s += __shfl_xor(s, 4, 64);
    s += __shfl_xor(s, 8, 64);
    rs[ii] = 1.f / s;
  }
  // write P bf16 to wave-private LDS [16][512B], swizzled
  char* pbase = smem + 32768 + wv * 8192;
  #pragma unroll
  for (int tb = 0; tb < 16; ++tb)
    #pragma unroll
    for (int ii = 0; ii < 4; ++ii) {
      int r = 4 * lq + ii, t = tb * 16 + lr;
      *(u16*)(pbase + r * 512 + ((t * 2) ^ ((r & 7) << 4))) = f2bf(accs[tb][ii] * rs[ii]);
    }

  f32x4 acco[8];
  #pragma unroll
  for (int i = 0; i < 8; ++i) acco[i] = (f32x4){0.f, 0.f, 0.f, 0.f};

  #pragma unroll
  for (int th = 0; th < 2; ++th) {
    __syncthreads();   // waves done reading K tile / prev V half + P writes visible to self
    #pragma unroll
    for (int it = 0; it < 8; ++it) {
      int chunk = it * 256 + tid;
      int row = chunk >> 4, slot = chunk & 15;
      short8 val = *(const short8*)(v + ((size_t)(b * 1024 + h * 128 + row)) * 256 + th * 128 + slot * 8);
      *(short8*)(smem + row * 256 + ((slot * 16) ^ ((row & 7) << 4))) = val;
    }
    __syncthreads();
    short8 pf[4];
    #pragma unroll
    for (int kk = 0; kk < 4; ++kk) {
      int cb = (th * 256 + kk * 64 + lq * 16);
      pf[kk] = *(const short8*)(pbase + lr * 512 + (cb ^ ((lr & 7) << 4)));
    }
    #pragma unroll
    for (int db = 0; db < 8; ++db)
      #pragma unroll
      for (int kk = 0; kk < 4; ++kk) {
        int vrow = db * 16 + lr;
        short8 bv = *(const short8*)(smem + vrow * 256 + ((kk * 64 + lq * 16) ^ ((vrow & 7) << 4)));
        acco[db] = __builtin_amdgcn_mfma_f32_16x16x32_bf16(pf[kk], bv, acco[db], 0, 0, 0);
      }
  }
  #pragma unroll
  for (int db = 0; db < 8; ++db)
    #pragma unroll
    for (int ii = 0; ii < 4; ++ii) {
      int n = nbase + 4 * lq + ii;
      o[((size_t)(b * 4096 + n)) * 1024 + h * 128 + db * 16 + lr] = f2bf(acco[db][ii]);
    }
}

extern "C" void kernel_launch(void* const* d_in, const int* in_sizes, int n_in,
                              void* d_out, int out_size, void* d_ws, size_t ws_size,
                              hipStream_t stream) {
  (void)in_sizes; (void)n_in; (void)out_size; (void)ws_size;
  const float* x  = (const float*)d_in[0];
  const float* l  = (const float*)d_in[1];
  const float* Wq = (const float*)d_in[2];
  const float* bq = (const float*)d_in[3];
  const float* gq = (const float*)d_in[4];
  const float* zq = (const float*)d_in[5];
  const float* Wk = (const float*)d_in[6];
  const float* bk = (const float*)d_in[7];
  const float* Wv = (const float*)d_in[8];
  const float* bv = (const float*)d_in[9];
  const float* Wo = (const float*)d_in[10];
  const float* bo = (const float*)d_in[11];
  const float* go = (const float*)d_in[12];
  const float* zo = (const float*)d_in[13];
  float* out = (float*)d_out;

  char* ws = (char*)d_ws;
  size_t off = 0;
  auto alloc = [&](size_t bytes) -> char* {
    char* p = ws + off;
    off += (bytes + 255) & ~(size_t)255;
    return p;
  };
  u16* xa  = (u16*)alloc((size_t)65536 * 1024 * 2);  // x bf16, later attn_out
  u16* qb  = (u16*)alloc((size_t)65536 * 1024 * 2);  // q (->qn in place), later out-gemm
  u16* wqb = (u16*)alloc((size_t)1024 * 1024 * 2);
  u16* wkb = (u16*)alloc((size_t)1024 * 768 * 2);
  u16* wvb = (u16*)alloc((size_t)1024 * 768 * 2);
  u16* wob = (u16*)alloc((size_t)1024 * 1024 * 2);
  u16* lTb = (u16*)alloc((size_t)16 * 256 * 768 * 2);
  u16* kTb = (u16*)alloc((size_t)16 * 256 * 1024 * 2);
  u16* vTb = (u16*)alloc((size_t)16 * 256 * 1024 * 2);
  u16* vb  = (u16*)alloc((size_t)16 * 1024 * 256 * 2);
  float* psum   = (float*)alloc((size_t)16 * 16 * 1024 * 4);
  float* psq    = (float*)alloc((size_t)16 * 16 * 1024 * 4);
  float* mean_s = (float*)alloc((size_t)16 * 1024 * 4);
  float* rstd_s = (float*)alloc((size_t)16 * 1024 * 4);

  // converts
  cvt_f32_bf16<<<2048, 256, 0, stream>>>(x, xa, 65536 * 1024 / 4);
  cvt_f32_bf16<<<512, 256, 0, stream>>>(Wq, wqb, 1024 * 1024 / 4);
  cvt_f32_bf16<<<512, 256, 0, stream>>>(Wk, wkb, 1024 * 768 / 4);
  cvt_f32_bf16<<<512, 256, 0, stream>>>(Wv, wvb, 1024 * 768 / 4);
  cvt_f32_bf16<<<512, 256, 0, stream>>>(Wo, wob, 1024 * 1024 / 4);
  // l transpose
  transpose_l<<<dim3(8, 24, 16), dim3(32, 8), 0, stream>>>(l, lTb);
  // Q = x Wq^T + bq
  gemm_bt<<<dim3(8, 512), 256, 0, stream>>>(xa, wqb, bq, qb, 65536, 1024, 1024);
  // GN(q) in place
  gn_stats_partial<<<dim3(16, 16), 256, 0, stream>>>(qb, psum, psq);
  gn_stats_final<<<64, 256, 0, stream>>>(psum, psq, mean_s, rstd_s);
  gn_norm_bf16<<<2048, 256, 0, stream>>>(qb, mean_s, rstd_s, gq, zq);
  // kT = lT Wk^T + bk ; vT = lT Wv^T + bv ; v = vT^T
  gemm_bt<<<dim3(8, 32), 256, 0, stream>>>(lTb, wkb, bk, kTb, 4096, 1024, 768);
  gemm_bt<<<dim3(8, 32), 256, 0, stream>>>(lTb, wvb, bv, vTb, 4096, 1024, 768);
  transpose_v<<<dim3(8, 32, 16), dim3(32, 8), 0, stream>>>(vTb, vb);
  // attention -> xa
  attn_kernel<<<dim3(64, 8, 16), 256, 0, stream>>>(qb, kTb, vb, xa);
  // out = attn_out Wo^T + bo -> qb
  gemm_bt<<<dim3(8, 512), 256, 0, stream>>>(xa, wob, bo, qb, 65536, 1024, 1024);
  // GN(out) -> f32 d_out
  gn_stats_partial<<<dim3(16, 16), 256, 0, stream>>>(qb, psum, psq);
  gn_stats_final<<<64, 256, 0, stream>>>(psum, psq, mean_s, rstd_s);
  gn_norm_f32<<<2048, 256, 0, stream>>>(qb, mean_s, rstd_s, go, zo, out);
}